// Round 1
// baseline (500.892 us; speedup 1.0000x reference)
//
#include <hip/hip_runtime.h>
#include <hip/hip_bf16.h>

// Problem constants (match reference)
#define NN 100000
#define EE 500000
#define HH 8
#define DKK 16
// grid sizes for edge passes
#define GRID1 1024
#define GRID2 1024

// Workspace layout (in floats)
// proj [N][384]  : k | qr | v per node
// s    [E][8]    : attention logits
// src32[E], dst32[E] (int)
// pmax [GRID1][8]
// m8   [8]
// part [GRID2][136]   (8 heads x (16 pooled + 1 Z))
// outv [128]
// Wall [384][128], ball[384]
static const long long OFF_PROJ = 0;
static const long long OFF_S    = OFF_PROJ + (long long)NN * 384;
static const long long OFF_SRC  = OFF_S + (long long)EE * 8;
static const long long OFF_DST  = OFF_SRC + EE;
static const long long OFF_PMAX = OFF_DST + EE;
static const long long OFF_M8   = OFF_PMAX + (long long)GRID1 * 8;
static const long long OFF_PART = OFF_M8 + 8;
static const long long OFF_OUTV = OFF_PART + (long long)GRID2 * 136;
static const long long OFF_WALL = OFF_OUTV + 128;
static const long long OFF_BALL = OFF_WALL + (long long)384 * 128;

// ---------------------------------------------------------------------------
// Build combined weight matrix W_all[384][128] and bias ball[384]:
//  rows 0..127   = Wk
//  rows 128..255 = Wq' (R_att folded in):  Wq'[h*16+d, c] = sum_f R_att[h,d,f]*Wq[h*16+f, c]
//  rows 256..383 = Wv
__global__ void build_wall(const float* __restrict__ Wk, const float* __restrict__ bk,
                           const float* __restrict__ Wq, const float* __restrict__ bq,
                           const float* __restrict__ Wv, const float* __restrict__ bv,
                           const float* __restrict__ R_att,
                           float* __restrict__ Wall, float* __restrict__ ball) {
    int j = blockIdx.x;      // 0..383
    int c = threadIdx.x;     // 0..127
    float w;
    if (j < 128) {
        w = Wk[j * 128 + c];
        if (c == 0) ball[j] = bk[j];
    } else if (j < 256) {
        int jj = j - 128;
        int h = jj >> 4, d = jj & 15;
        float s = 0.f;
        #pragma unroll
        for (int f = 0; f < 16; ++f)
            s += R_att[h * 256 + d * 16 + f] * Wq[(h * 16 + f) * 128 + c];
        w = s;
        if (c == 0) {
            float sb = 0.f;
            for (int f = 0; f < 16; ++f)
                sb += R_att[h * 256 + d * 16 + f] * bq[h * 16 + f];
            ball[j] = sb;
        }
    } else {
        int jj = j - 256;
        w = Wv[jj * 128 + c];
        if (c == 0) ball[j] = bv[jj];
    }
    Wall[j * 128 + c] = w;
}

// ---------------------------------------------------------------------------
// Detect int64 vs int32 edge_index layout and convert to int32 src/dst.
__global__ void convert_idx(const int* __restrict__ ei, int* __restrict__ src32,
                            int* __restrict__ dst32, int E_) {
    __shared__ unsigned int red[256];
    int tid = threadIdx.x;
    const unsigned int* w = (const unsigned int*)ei;
    // probe: if data is int64, high words (odd ints) of first 256 entries are 0.
    red[tid] = w[2 * tid + 1];
    __syncthreads();
    for (int st = 128; st > 0; st >>= 1) {
        if (tid < st) red[tid] |= red[tid + st];
        __syncthreads();
    }
    bool is64 = (red[0] == 0u);
    for (int e = blockIdx.x * blockDim.x + tid; e < E_; e += gridDim.x * blockDim.x) {
        if (is64) {
            src32[e] = ei[2 * e];             // low word (little-endian)
            dst32[e] = ei[2 * (E_ + e)];
        } else {
            src32[e] = ei[e];
            dst32[e] = ei[E_ + e];
        }
    }
}

// ---------------------------------------------------------------------------
// Fused projection GEMM: proj[n, 0:384] = x[n,:] @ Wall^T + ball
// Tiled 64x64, fp32, K=128 fully resident in LDS.
__global__ __launch_bounds__(256) void proj_gemm(const float* __restrict__ x,
                                                 const float* __restrict__ Wall,
                                                 const float* __restrict__ ball,
                                                 float* __restrict__ proj) {
    __shared__ float As[64][132];
    __shared__ float Bs[64][132];
    int row0 = blockIdx.x * 64;
    int col0 = blockIdx.y * 64;   // 0,64,...,320
    int tid = threadIdx.x;

    // load tiles (64 rows x 128 cols each), float4
    for (int t = tid; t < 64 * 32; t += 256) {
        int r = t >> 5, c4 = t & 31;
        float4 val;
        int gr = row0 + r;
        if (gr < NN) val = ((const float4*)(x + (long long)gr * 128))[c4];
        else val = make_float4(0.f, 0.f, 0.f, 0.f);
        *(float4*)&As[r][c4 * 4] = val;
    }
    for (int t = tid; t < 64 * 32; t += 256) {
        int r = t >> 5, c4 = t & 31;
        float4 val = ((const float4*)(Wall + (long long)(col0 + r) * 128))[c4];
        *(float4*)&Bs[r][c4 * 4] = val;
    }
    __syncthreads();

    int tm = tid >> 4, tn = tid & 15;  // 16x16 thread grid, each 4x4 outputs
    float acc[4][4] = {};
    for (int k = 0; k < 128; k += 4) {
        float4 a[4], b[4];
        #pragma unroll
        for (int i = 0; i < 4; ++i) a[i] = *(const float4*)&As[tm * 4 + i][k];
        #pragma unroll
        for (int j = 0; j < 4; ++j) b[j] = *(const float4*)&Bs[tn * 4 + j][k];
        #pragma unroll
        for (int i = 0; i < 4; ++i)
            #pragma unroll
            for (int j = 0; j < 4; ++j)
                acc[i][j] += a[i].x * b[j].x + a[i].y * b[j].y + a[i].z * b[j].z + a[i].w * b[j].w;
    }
    #pragma unroll
    for (int i = 0; i < 4; ++i) {
        int gr = row0 + tm * 4 + i;
        if (gr >= NN) continue;
        #pragma unroll
        for (int j = 0; j < 4; ++j) {
            int gc = col0 + tn * 4 + j;
            proj[(long long)gr * 384 + gc] = acc[i][j] + ball[gc];
        }
    }
}

// ---------------------------------------------------------------------------
// Edge pass 1: s[e,h] = (k[src,h,:]·qr[dst,h,:]) * R_pri[h]/4 ; per-head block max
__global__ __launch_bounds__(256) void edge_pass1(const float* __restrict__ proj,
                                                  const int* __restrict__ src32,
                                                  const int* __restrict__ dst32,
                                                  const float* __restrict__ R_pri,
                                                  float* __restrict__ s_out,
                                                  float* __restrict__ pmax) {
    __shared__ float red[256];
    int tid = threadIdx.x;
    int sub = tid & 7;        // head
    int eslot = tid >> 3;     // 0..31
    float rp = R_pri[sub] * 0.25f;
    float lmax = -INFINITY;
    for (int base = blockIdx.x * 32; base < EE; base += GRID1 * 32) {
        int e = base + eslot;
        if (e < EE) {
            int sn = src32[e], dn = dst32[e];
            const float4* kp = (const float4*)(proj + (long long)sn * 384 + sub * 16);
            const float4* qp = (const float4*)(proj + (long long)dn * 384 + 128 + sub * 16);
            float dot = 0.f;
            #pragma unroll
            for (int i = 0; i < 4; ++i) {
                float4 a = kp[i], b = qp[i];
                dot += a.x * b.x + a.y * b.y + a.z * b.z + a.w * b.w;
            }
            float sv = dot * rp;
            s_out[(long long)e * 8 + sub] = sv;
            lmax = fmaxf(lmax, sv);
        }
    }
    red[tid] = lmax;
    __syncthreads();
    for (int st = 128; st >= 8; st >>= 1) {
        if (tid < st) red[tid] = fmaxf(red[tid], red[tid + st]);
        __syncthreads();
    }
    if (tid < 8) pmax[blockIdx.x * 8 + tid] = red[tid];
}

__global__ void reduce_max(const float* __restrict__ pmax, float* __restrict__ m8) {
    __shared__ float red[256];
    int tid = threadIdx.x;
    int h = tid & 7;
    float lm = -INFINITY;
    for (int b = tid >> 3; b < GRID1; b += 32) lm = fmaxf(lm, pmax[b * 8 + h]);
    red[tid] = lm;
    __syncthreads();
    for (int st = 128; st >= 8; st >>= 1) {
        if (tid < st) red[tid] = fmaxf(red[tid], red[tid + st]);
        __syncthreads();
    }
    if (tid < 8) m8[tid] = red[tid];
}

// ---------------------------------------------------------------------------
// Edge pass 2: w = exp(s - m); pooled[h,d] += w * v[src,h,d]; Z[h] += w
// Per-block partials written deterministically.
__global__ __launch_bounds__(256) void edge_pass2(const float* __restrict__ proj,
                                                  const int* __restrict__ src32,
                                                  const float* __restrict__ s_in,
                                                  const float* __restrict__ m8,
                                                  float* __restrict__ partial) {
    __shared__ float red[256][18];
    int tid = threadIdx.x;
    int sub = tid & 7;
    int eslot = tid >> 3;
    float m = m8[sub];
    float acc[16] = {};
    float zacc = 0.f;
    for (int base = blockIdx.x * 32; base < EE; base += GRID2 * 32) {
        int e = base + eslot;
        if (e < EE) {
            float w = __expf(s_in[(long long)e * 8 + sub] - m);
            zacc += w;
            int sn = src32[e];
            const float4* vp = (const float4*)(proj + (long long)sn * 384 + 256 + sub * 16);
            #pragma unroll
            for (int i = 0; i < 4; ++i) {
                float4 v4 = vp[i];
                acc[i * 4 + 0] += w * v4.x;
                acc[i * 4 + 1] += w * v4.y;
                acc[i * 4 + 2] += w * v4.z;
                acc[i * 4 + 3] += w * v4.w;
            }
        }
    }
    #pragma unroll
    for (int v = 0; v < 16; ++v) red[tid][v] = acc[v];
    red[tid][16] = zacc;
    __syncthreads();
    for (int st = 128; st >= 8; st >>= 1) {
        if (tid < st) {
            #pragma unroll
            for (int v = 0; v < 17; ++v) red[tid][v] += red[tid + st][v];
        }
        __syncthreads();
    }
    // rows 0..7 hold per-head sums (stride multiples of 8 preserve head)
    if (tid < 136) partial[blockIdx.x * 136 + tid] = red[tid / 17][tid % 17];
}

// ---------------------------------------------------------------------------
// Finalize: reduce partials -> pooled/Z -> apply R_msg -> Wa -> alpha scale
__global__ void finalize(const float* __restrict__ partial,
                         const float* __restrict__ R_msg,
                         const float* __restrict__ Wa, const float* __restrict__ ba,
                         const float* __restrict__ skip,
                         float* __restrict__ outv) {
    __shared__ float pooled[8][16];
    __shared__ float Zs[8];
    __shared__ float pn[8][16];
    __shared__ float msg[128];
    int tid = threadIdx.x;
    if (tid < 136) {
        float sum = 0.f;
        for (int b = 0; b < GRID2; ++b) sum += partial[b * 136 + tid];
        int h = tid / 17, v = tid % 17;
        if (v < 16) pooled[h][v] = sum;
        else Zs[h] = sum;
    }
    __syncthreads();
    if (tid < 128) {
        int h = tid >> 4, d = tid & 15;
        pn[h][d] = pooled[h][d] / Zs[h];
    }
    __syncthreads();
    if (tid < 128) {
        int h = tid >> 4, f = tid & 15;
        float s = 0.f;
        #pragma unroll
        for (int d = 0; d < 16; ++d) s += pn[h][d] * R_msg[h * 256 + d * 16 + f];
        msg[tid] = s;   // flat index h*16+f == tid
    }
    __syncthreads();
    if (tid < 128) {
        float s = ba[tid];
        for (int j = 0; j < 128; ++j) s += Wa[tid * 128 + j] * msg[j];
        float alpha = 1.f / (1.f + __expf(-skip[0]));
        outv[tid] = s * alpha;
    }
}

// ---------------------------------------------------------------------------
// Broadcast: out[n,c] = outv[c] (already *alpha) + (1-alpha)*x[n,c]
__global__ __launch_bounds__(256) void broadcast_out(const float* __restrict__ x,
                                                     const float* __restrict__ outv,
                                                     const float* __restrict__ skip,
                                                     float* __restrict__ out) {
    float alpha = 1.f / (1.f + __expf(-skip[0]));
    float beta = 1.f - alpha;
    const int total4 = NN * 128 / 4;
    for (int i = blockIdx.x * blockDim.x + threadIdx.x; i < total4;
         i += gridDim.x * blockDim.x) {
        float4 xv = ((const float4*)x)[i];
        int c4 = i & 31;
        float4 ov = ((const float4*)outv)[c4];
        float4 r;
        r.x = ov.x + beta * xv.x;
        r.y = ov.y + beta * xv.y;
        r.z = ov.z + beta * xv.z;
        r.w = ov.w + beta * xv.w;
        ((float4*)out)[i] = r;
    }
}

// ---------------------------------------------------------------------------
extern "C" void kernel_launch(void* const* d_in, const int* in_sizes, int n_in,
                              void* d_out, int out_size, void* d_ws, size_t ws_size,
                              hipStream_t stream) {
    const float* x      = (const float*)d_in[0];
    const int*   ei     = (const int*)d_in[1];
    const float* Wk     = (const float*)d_in[2];
    const float* bk     = (const float*)d_in[3];
    const float* Wq     = (const float*)d_in[4];
    const float* bq     = (const float*)d_in[5];
    const float* Wv     = (const float*)d_in[6];
    const float* bv     = (const float*)d_in[7];
    const float* Wa     = (const float*)d_in[8];
    const float* ba     = (const float*)d_in[9];
    const float* R_att  = (const float*)d_in[10];
    const float* R_msg  = (const float*)d_in[11];
    const float* R_pri  = (const float*)d_in[12];
    const float* skip   = (const float*)d_in[13];
    float* out = (float*)d_out;
    float* ws  = (float*)d_ws;

    float* proj  = ws + OFF_PROJ;
    float* s_buf = ws + OFF_S;
    int*   src32 = (int*)(ws + OFF_SRC);
    int*   dst32 = (int*)(ws + OFF_DST);
    float* pmax  = ws + OFF_PMAX;
    float* m8    = ws + OFF_M8;
    float* part  = ws + OFF_PART;
    float* outv  = ws + OFF_OUTV;
    float* Wall  = ws + OFF_WALL;
    float* ball  = ws + OFF_BALL;

    build_wall<<<384, 128, 0, stream>>>(Wk, bk, Wq, bq, Wv, bv, R_att, Wall, ball);
    convert_idx<<<512, 256, 0, stream>>>(ei, src32, dst32, EE);
    dim3 gg((NN + 63) / 64, 6);
    proj_gemm<<<gg, 256, 0, stream>>>(x, Wall, ball, proj);
    edge_pass1<<<GRID1, 256, 0, stream>>>(proj, src32, dst32, R_pri, s_buf, pmax);
    reduce_max<<<1, 256, 0, stream>>>(pmax, m8);
    edge_pass2<<<GRID2, 256, 0, stream>>>(proj, src32, s_buf, m8, part);
    finalize<<<1, 256, 0, stream>>>(part, R_msg, Wa, ba, skip, outv);
    broadcast_out<<<2048, 256, 0, stream>>>(x, outv, skip, out);
}

// Round 2
// 279.959 us; speedup vs baseline: 1.7892x; 1.7892x over previous
//
#include <hip/hip_runtime.h>
#include <hip/hip_bf16.h>

// Problem constants (match reference)
#define NN 100000
#define EE 500000
#define HH 8
#define DKK 16
#define GRIDE 768   // edge_fused blocks (3 per CU)

typedef __attribute__((ext_vector_type(8))) __bf16 bf16x8;
typedef __attribute__((ext_vector_type(4))) float f32x4;

// Workspace layout (float units)
// projb [N][384] bf16 : k | qr | v per node (h*16 contiguous per head)
// src32[E], dst32[E] (int)
// partial [GRIDE][8][18] : per-block per-head {acc[16], Z, m}
// outv[128], Wallb[384][128] bf16, ball[384] f32
static const long long OFF_PROJ = 0;                                   // 19,200,000 floats (bf16)
static const long long OFF_SRC  = 19200000;
static const long long OFF_DST  = 19700000;
static const long long OFF_PART = 20200000;                            // 768*144 = 110592
static const long long OFF_OUTV = 20310592;
static const long long OFF_WALL = 20310720;                            // 384*128 bf16 = 24576 floats
static const long long OFF_BALL = 20335296;

__device__ inline unsigned short f2bf(float f) {
    unsigned int u = __float_as_uint(f);
    unsigned int r = (u + 0x7FFFu + ((u >> 16) & 1u)) >> 16;   // RNE
    return (unsigned short)r;
}
__device__ inline unsigned int pack2bf(float a, float b) {
    return (unsigned int)f2bf(a) | ((unsigned int)f2bf(b) << 16);
}
#define LOF(u) __uint_as_float((u) << 16)
#define HIF(u) __uint_as_float((u) & 0xffff0000u)

// ---------------------------------------------------------------------------
// Build combined weight matrix Wallb[384][128] (bf16) and bias ball[384] (f32):
//  rows 0..127 = Wk ; 128..255 = Wq' (R_att folded) ; 256..383 = Wv
__global__ void build_wall(const float* __restrict__ Wk, const float* __restrict__ bk,
                           const float* __restrict__ Wq, const float* __restrict__ bq,
                           const float* __restrict__ Wv, const float* __restrict__ bv,
                           const float* __restrict__ R_att,
                           unsigned short* __restrict__ Wallb, float* __restrict__ ball) {
    int j = blockIdx.x;      // 0..383
    int c = threadIdx.x;     // 0..127
    float w;
    if (j < 128) {
        w = Wk[j * 128 + c];
        if (c == 0) ball[j] = bk[j];
    } else if (j < 256) {
        int jj = j - 128;
        int h = jj >> 4, d = jj & 15;
        float s = 0.f;
        #pragma unroll
        for (int f = 0; f < 16; ++f)
            s += R_att[h * 256 + d * 16 + f] * Wq[(h * 16 + f) * 128 + c];
        w = s;
        if (c == 0) {
            float sb = 0.f;
            for (int f = 0; f < 16; ++f)
                sb += R_att[h * 256 + d * 16 + f] * bq[h * 16 + f];
            ball[j] = sb;
        }
    } else {
        int jj = j - 256;
        w = Wv[jj * 128 + c];
        if (c == 0) ball[j] = bv[jj];
    }
    Wallb[j * 128 + c] = f2bf(w);
}

// ---------------------------------------------------------------------------
// Detect int64 vs int32 edge_index layout and convert to int32 src/dst.
__global__ void convert_idx(const int* __restrict__ ei, int* __restrict__ src32,
                            int* __restrict__ dst32, int E_) {
    __shared__ unsigned int red[256];
    int tid = threadIdx.x;
    const unsigned int* w = (const unsigned int*)ei;
    red[tid] = w[2 * tid + 1];
    __syncthreads();
    for (int st = 128; st > 0; st >>= 1) {
        if (tid < st) red[tid] |= red[tid + st];
        __syncthreads();
    }
    bool is64 = (red[0] == 0u);
    for (int e = blockIdx.x * blockDim.x + tid; e < E_; e += gridDim.x * blockDim.x) {
        if (is64) {
            src32[e] = ei[2 * e];
            dst32[e] = ei[2 * (E_ + e)];
        } else {
            src32[e] = ei[e];
            dst32[e] = ei[E_ + e];
        }
    }
}

// ---------------------------------------------------------------------------
// MFMA projection GEMM: projb[n, 0:384] = bf16( x[n,:] @ Wallb^T + ball )
// 128x128 tile, K=128 single shot, 4 waves, 16x16x32 bf16 MFMA.
// LDS 16B-slot XOR swizzle (slot ^ (row&15)) on both write and read sides.
__global__ __launch_bounds__(256) void proj_gemm_mfma(const float* __restrict__ x,
                                                      const unsigned short* __restrict__ Wallb,
                                                      const float* __restrict__ ball,
                                                      unsigned short* __restrict__ projb) {
    __shared__ __align__(16) char smem[65536];
    unsigned short* As = (unsigned short*)smem;            // [128][128] bf16 swizzled
    unsigned short* Bs = (unsigned short*)(smem + 32768);  // [128][128] bf16 swizzled
    int tid = threadIdx.x;
    long long row0 = (long long)blockIdx.x * 128;
    int col0 = blockIdx.y * 128;   // 0,128,256

    // Stage A: x fp32 -> bf16 (2048 chunks of 8 bf16)
    for (int c = tid; c < 2048; c += 256) {
        int r = c >> 4, sl = c & 15;
        long long gr = row0 + r;
        float4 v0, v1;
        if (gr < NN) {
            const float4* xp = (const float4*)(x + gr * 128 + sl * 8);
            v0 = xp[0]; v1 = xp[1];
        } else {
            v0 = make_float4(0.f, 0.f, 0.f, 0.f);
            v1 = make_float4(0.f, 0.f, 0.f, 0.f);
        }
        uint4 pk;
        pk.x = pack2bf(v0.x, v0.y); pk.y = pack2bf(v0.z, v0.w);
        pk.z = pack2bf(v1.x, v1.y); pk.w = pack2bf(v1.z, v1.w);
        int ps = sl ^ (r & 15);
        *(uint4*)(As + r * 128 + ps * 8) = pk;
    }
    // Stage B: Wallb bf16 passthrough
    for (int c = tid; c < 2048; c += 256) {
        int r = c >> 4, sl = c & 15;
        uint4 v = *(const uint4*)(Wallb + (long long)(col0 + r) * 128 + sl * 8);
        int ps = sl ^ (r & 15);
        *(uint4*)(Bs + r * 128 + ps * 8) = v;
    }
    __syncthreads();

    int lane = tid & 63, wv = tid >> 6, wr = wv >> 1, wc = wv & 1;
    int lrow = lane & 15, lk = lane >> 4;
    f32x4 acc[4][4];
    #pragma unroll
    for (int m = 0; m < 4; ++m)
        #pragma unroll
        for (int n = 0; n < 4; ++n)
            acc[m][n] = f32x4{0.f, 0.f, 0.f, 0.f};

    #pragma unroll
    for (int kk = 0; kk < 4; ++kk) {
        int kc = kk * 4 + lk;
        bf16x8 a[4], b[4];
        #pragma unroll
        for (int m = 0; m < 4; ++m) {
            int r = wr * 64 + m * 16 + lrow;
            a[m] = *(const bf16x8*)(As + r * 128 + (kc ^ (r & 15)) * 8);
        }
        #pragma unroll
        for (int n = 0; n < 4; ++n) {
            int r = wc * 64 + n * 16 + lrow;
            b[n] = *(const bf16x8*)(Bs + r * 128 + (kc ^ (r & 15)) * 8);
        }
        #pragma unroll
        for (int m = 0; m < 4; ++m)
            #pragma unroll
            for (int n = 0; n < 4; ++n)
                acc[m][n] = __builtin_amdgcn_mfma_f32_16x16x32_bf16(a[m], b[n], acc[m][n], 0, 0, 0);
    }
    __syncthreads();

    // Epilogue: bias add, cvt bf16, transpose through LDS for vectorized stores
    unsigned short* Cs = (unsigned short*)smem;  // [128][128] bf16 linear (aliases As)
    float bias[4];
    #pragma unroll
    for (int n = 0; n < 4; ++n) bias[n] = ball[col0 + wc * 64 + n * 16 + lrow];
    #pragma unroll
    for (int m = 0; m < 4; ++m) {
        int rb = wr * 64 + m * 16 + lk * 4;
        #pragma unroll
        for (int n = 0; n < 4; ++n) {
            int cb = wc * 64 + n * 16 + lrow;
            #pragma unroll
            for (int r = 0; r < 4; ++r)
                Cs[(rb + r) * 128 + cb] = f2bf(acc[m][n][r] + bias[n]);
        }
    }
    __syncthreads();
    for (int c = tid; c < 2048; c += 256) {
        int r = c >> 4, sl = c & 15;
        long long gr = row0 + r;
        if (gr < NN)
            *(uint4*)(projb + gr * 384 + col0 + sl * 8) = *(const uint4*)(Cs + r * 128 + sl * 8);
    }
}

// ---------------------------------------------------------------------------
// Fused edge pass: online softmax. Thread = (edge-slot, head).
// s = (k[src]·qr[dst]) * R_pri/4 ; running (m, Z, acc[16]) with branchless rescale.
// Block tree-merge (max-aware) -> partial[b][h][18] = {acc[16], Z, m}.
__global__ __launch_bounds__(256) void edge_fused(const unsigned short* __restrict__ projb,
                                                  const int* __restrict__ src32,
                                                  const int* __restrict__ dst32,
                                                  const float* __restrict__ R_pri,
                                                  float* __restrict__ partial) {
    __shared__ float red[256][18];
    int tid = threadIdx.x;
    int h = tid & 7;
    int es = tid >> 3;
    float rp = R_pri[h] * 0.25f;
    float m = -1e30f, Z = 0.f;
    float acc[16];
    #pragma unroll
    for (int d = 0; d < 16; ++d) acc[d] = 0.f;

    for (int base = blockIdx.x * 32; base < EE; base += GRIDE * 32) {
        int e = base + es;
        int ee = min(e, EE - 1);
        int sn = src32[ee], dn = dst32[ee];
        const uint4* kp = (const uint4*)(projb + (size_t)sn * 384 + h * 16);
        const uint4* qp = (const uint4*)(projb + (size_t)dn * 384 + 128 + h * 16);
        const uint4* vp = (const uint4*)(projb + (size_t)sn * 384 + 256 + h * 16);
        uint4 k0 = kp[0], k1 = kp[1];
        uint4 q0 = qp[0], q1 = qp[1];
        uint4 v0 = vp[0], v1 = vp[1];
        float dot = 0.f;
        #define DOT2(kw, qw) dot = fmaf(LOF(kw), LOF(qw), dot); dot = fmaf(HIF(kw), HIF(qw), dot);
        DOT2(k0.x, q0.x) DOT2(k0.y, q0.y) DOT2(k0.z, q0.z) DOT2(k0.w, q0.w)
        DOT2(k1.x, q1.x) DOT2(k1.y, q1.y) DOT2(k1.z, q1.z) DOT2(k1.w, q1.w)
        #undef DOT2
        float s = dot * rp;
        if (e >= EE) s = -INFINITY;     // masked lane: w -> 0, m unchanged
        float mn = fmaxf(m, s);
        float c0 = __expf(m - mn);      // 1 if max unchanged; underflows to 0 on first edge
        float w  = __expf(s - mn);
        Z = Z * c0 + w;
        m = mn;
        #define ACC2(i, vw) { acc[2*(i)]   = fmaf(w, LOF(vw), acc[2*(i)]   * c0); \
                              acc[2*(i)+1] = fmaf(w, HIF(vw), acc[2*(i)+1] * c0); }
        ACC2(0, v0.x) ACC2(1, v0.y) ACC2(2, v0.z) ACC2(3, v0.w)
        ACC2(4, v1.x) ACC2(5, v1.y) ACC2(6, v1.z) ACC2(7, v1.w)
        #undef ACC2
    }

    #pragma unroll
    for (int d = 0; d < 16; ++d) red[tid][d] = acc[d];
    red[tid][16] = Z;
    red[tid][17] = m;
    __syncthreads();
    for (int st = 128; st >= 8; st >>= 1) {
        if (tid < st) {
            float m1 = red[tid][17], m2 = red[tid + st][17];
            float M = fmaxf(m1, m2);
            float f1 = __expf(m1 - M), f2 = __expf(m2 - M);
            #pragma unroll
            for (int v = 0; v < 17; ++v)
                red[tid][v] = red[tid][v] * f1 + red[tid + st][v] * f2;
            red[tid][17] = M;
        }
        __syncthreads();
    }
    if (tid < 8) {
        for (int v = 0; v < 18; ++v)
            partial[blockIdx.x * 144 + tid * 18 + v] = red[tid][v];
    }
}

// ---------------------------------------------------------------------------
// Finalize: global max-merge of partials -> pooled/Z -> R_msg -> Wa -> alpha
__global__ void finalize(const float* __restrict__ partial,
                         const float* __restrict__ R_msg,
                         const float* __restrict__ Wa, const float* __restrict__ ba,
                         const float* __restrict__ skip,
                         float* __restrict__ outv) {
    __shared__ float red[512];
    __shared__ float Ms[8];
    __shared__ float colred[136][2];
    __shared__ float pooledZ[136];
    __shared__ float pn[128];
    __shared__ float msg[128];
    int tid = threadIdx.x;
    // phase A: per-head global max over GRIDE blocks
    {
        int h = tid & 7;
        float lm = -1e30f;
        for (int b = tid >> 3; b < GRIDE; b += 64)
            lm = fmaxf(lm, partial[b * 144 + h * 18 + 17]);
        red[tid] = lm;
        __syncthreads();
        for (int st = 256; st >= 8; st >>= 1) {
            if (tid < st) red[tid] = fmaxf(red[tid], red[tid + st]);
            __syncthreads();
        }
        if (tid < 8) Ms[tid] = red[tid];
    }
    __syncthreads();
    // phase B: weighted column sums (2 threads per column)
    if (tid < 272) {
        int col = tid >> 1, q = tid & 1;
        int h = col / 17, v = col % 17;
        float M = Ms[h];
        float sum = 0.f;
        for (int b = q; b < GRIDE; b += 2) {
            float w = __expf(partial[b * 144 + h * 18 + 17] - M);
            sum = fmaf(partial[b * 144 + h * 18 + v], w, sum);
        }
        colred[col][q] = sum;
    }
    __syncthreads();
    if (tid < 136) pooledZ[tid] = colred[tid][0] + colred[tid][1];
    __syncthreads();
    if (tid < 128) {
        int h = tid >> 4, d = tid & 15;
        pn[tid] = pooledZ[h * 17 + d] / pooledZ[h * 17 + 16];
    }
    __syncthreads();
    if (tid < 128) {
        int h = tid >> 4, f = tid & 15;
        float s = 0.f;
        #pragma unroll
        for (int d = 0; d < 16; ++d)
            s = fmaf(pn[h * 16 + d], R_msg[h * 256 + d * 16 + f], s);
        msg[tid] = s;
    }
    __syncthreads();
    if (tid < 128) {
        float s = ba[tid];
        for (int j = 0; j < 128; ++j) s = fmaf(Wa[tid * 128 + j], msg[j], s);
        float alpha = 1.f / (1.f + __expf(-skip[0]));
        outv[tid] = s * alpha;
    }
}

// ---------------------------------------------------------------------------
// Broadcast: out[n,c] = outv[c] (already *alpha) + (1-alpha)*x[n,c]
__global__ __launch_bounds__(256) void broadcast_out(const float* __restrict__ x,
                                                     const float* __restrict__ outv,
                                                     const float* __restrict__ skip,
                                                     float* __restrict__ out) {
    float alpha = 1.f / (1.f + __expf(-skip[0]));
    float beta = 1.f - alpha;
    const int total4 = NN * 128 / 4;
    for (int i = blockIdx.x * blockDim.x + threadIdx.x; i < total4;
         i += gridDim.x * blockDim.x) {
        float4 xv = ((const float4*)x)[i];
        int c4 = i & 31;
        float4 ov = ((const float4*)outv)[c4];
        float4 r;
        r.x = ov.x + beta * xv.x;
        r.y = ov.y + beta * xv.y;
        r.z = ov.z + beta * xv.z;
        r.w = ov.w + beta * xv.w;
        ((float4*)out)[i] = r;
    }
}

// ---------------------------------------------------------------------------
extern "C" void kernel_launch(void* const* d_in, const int* in_sizes, int n_in,
                              void* d_out, int out_size, void* d_ws, size_t ws_size,
                              hipStream_t stream) {
    const float* x      = (const float*)d_in[0];
    const int*   ei     = (const int*)d_in[1];
    const float* Wk     = (const float*)d_in[2];
    const float* bk     = (const float*)d_in[3];
    const float* Wq     = (const float*)d_in[4];
    const float* bq     = (const float*)d_in[5];
    const float* Wv     = (const float*)d_in[6];
    const float* bv     = (const float*)d_in[7];
    const float* Wa     = (const float*)d_in[8];
    const float* ba     = (const float*)d_in[9];
    const float* R_att  = (const float*)d_in[10];
    const float* R_msg  = (const float*)d_in[11];
    const float* R_pri  = (const float*)d_in[12];
    const float* skip   = (const float*)d_in[13];
    float* out = (float*)d_out;
    float* ws  = (float*)d_ws;

    unsigned short* projb = (unsigned short*)(ws + OFF_PROJ);
    int*   src32 = (int*)(ws + OFF_SRC);
    int*   dst32 = (int*)(ws + OFF_DST);
    float* part  = ws + OFF_PART;
    float* outv  = ws + OFF_OUTV;
    unsigned short* Wallb = (unsigned short*)(ws + OFF_WALL);
    float* ball  = ws + OFF_BALL;

    build_wall<<<384, 128, 0, stream>>>(Wk, bk, Wq, bq, Wv, bv, R_att, Wallb, ball);
    convert_idx<<<512, 256, 0, stream>>>(ei, src32, dst32, EE);
    dim3 gg((NN + 127) / 128, 3);
    proj_gemm_mfma<<<gg, 256, 0, stream>>>(x, Wallb, ball, projb);
    edge_fused<<<GRIDE, 256, 0, stream>>>(projb, src32, dst32, R_pri, part);
    finalize<<<1, 512, 0, stream>>>(part, R_msg, Wa, ba, skip, outv);
    broadcast_out<<<2048, 256, 0, stream>>>(x, outv, skip, out);
}